// Round 3
// baseline (251.753 us; speedup 1.0000x reference)
//
#include <hip/hip_runtime.h>

typedef _Float16 half8 __attribute__((ext_vector_type(8)));
typedef _Float16 half4v __attribute__((ext_vector_type(4)));
typedef _Float16 half2v __attribute__((ext_vector_type(2)));
typedef float floatx4 __attribute__((ext_vector_type(4)));

#define AS3 __attribute__((address_space(3)))
#define AS1 __attribute__((address_space(1)))

// async global->LDS, 16B per lane, wave-uniform LDS base + lane*16
__device__ __forceinline__ void gload_lds16(const _Float16* g, _Float16* l) {
    __builtin_amdgcn_global_load_lds((AS1 void*)g, (AS3 void*)l, 16, 0, 0);
}

__device__ __forceinline__ floatx4 mfma16(half8 a, half8 b, floatx4 c) {
    return __builtin_amdgcn_mfma_f32_16x16x32_f16(a, b, c, 0, 0, 0);
}

// ---------------- fused f32 -> f16 convert of all three inputs ----------------
__global__ __launch_bounds__(256) void cvt_all(const float* __restrict__ x,
                                               const float* __restrict__ wq,
                                               const float* __restrict__ wp,
                                               _Float16* __restrict__ xh,
                                               _Float16* __restrict__ wqh,
                                               _Float16* __restrict__ wph) {
    long i = (long)blockIdx.x * 256 + threadIdx.x;   // float4 index
    const float4* src; half4v* dst; long off;
    if (i < 2097152)      { src = (const float4*)x;  dst = (half4v*)xh;  off = i; }
    else if (i < 2883584) { src = (const float4*)wq; dst = (half4v*)wqh; off = i - 2097152; }
    else                  { src = (const float4*)wp; dst = (half4v*)wph; off = i - 2883584; }
    float4 v = src[off];
    half4v h = {(_Float16)v.x, (_Float16)v.y, (_Float16)v.z, (_Float16)v.w};
    dst[off] = h;
}

// ---------------- 256x256 8-phase TN GEMM (QKV) ------------------------------
// C[M,N] = A[M,K] * B[N,K]^T.  BM=BN=256, BK=64, 512 threads = 2x4 waves.
// R9: 8-phase counted-vmcnt schedule (T2+T3+T4+T5, m201 template) with the
// stage stream corrected for THIS quadrant order (R8 raced: A0(t+2)@P2
// overwrote cur-buf A rows still ds_read at P3).
// WAR audit: A slot (buf,half) last read at P3 (qm=1 frags) -> A-targeting
// cur-buf stages legal only at P4.  B slot last read at P2 (qn=1 frags) ->
// legal at P3/P4.  Stream: P1 -> A1(t+1) (OTHER buf, last read t-1 P3),
// P2 -> none, P3 -> B0(t+2), P4 -> B1(t+2) + A0(t+2).
// vmcnt: outstanding at P4-end = 14 (6 from t-1 {B0,B1,A0}(t+1), 8 from t);
// vmcnt(6) retires oldest 8 = tile t+1 exactly.  Per-wave count + barrier.
// Drain: vmcnt(0) at t==NT-2.  Never 0 in steady state (T4).
// LDS 128 KiB: {A,B} x 2 dbuf x 2 half-tiles of [128 rows][64 k] f16.
// Per wave: output 128x64 = acc[8][4].  Quadrant order Q00,Q01,Q11,Q10:
// P1 reads A(qm0)+B(qn0), P2 reads B(qn1), P3 reads A(qm1), P4 reads nothing
// (b0 and afr(qm1) still live) — minimizes frag registers (afr reused).
// Bank swizzle (rule #21, both-sides): LDS chunk c of row r holds global
// chunk c^(r&7); staged with LINEAR gload_lds dest + pre-swizzled GLOBAL
// source (per-thread chunk (tid&7)^((tid>>3)&7), loop-invariant); ds_read at
// chunk (ks*4+quad)^(l16&7) — 8-lane groups hit 8 distinct 16B slots, <=2-way
// bank aliasing (free, m136).
// Epilogue: cols<split -> Ch row-major f16; cols>=split -> Vt transposed
// (QKV-specific: row>>10 = b, (col-split)>>6 = h).
__global__ __launch_bounds__(512, 2) void gemm256_qkv(
    const _Float16* __restrict__ A, const _Float16* __restrict__ B,
    _Float16* __restrict__ Ch, int ldc, _Float16* __restrict__ Vt, int split,
    int K)
{
    __shared__ _Float16 sA[2 * 2 * 8192];   // [dbuf][half][128*64]
    __shared__ _Float16 sB[2 * 2 * 8192];

    // bijective XCD swizzle (grid 384 % 8 == 0)
    const int nwg = gridDim.x * gridDim.y;
    int bid = blockIdx.y * gridDim.x + blockIdx.x;
    const int cpx = nwg >> 3;
    bid = (bid & 7) * cpx + (bid >> 3);
    const int bx = bid % gridDim.x, by = bid / gridDim.x;

    const int tid = threadIdx.x;
    const int lane = tid & 63, wave = tid >> 6;
    const int quad = lane >> 4, l16 = lane & 15;
    const int wm = wave >> 2, wn = wave & 3;      // 2 x 4 wave grid
    const int hB = wn >> 1;                       // B half this wave reads
    const long m0 = (long)bx * 256, n0 = (long)by * 256;

    // pre-swizzled global source chunk (see header comment)
    const int gch = ((tid & 7) ^ ((tid >> 3) & 7)) * 8;
    const _Float16* gA = A + (m0 + (tid >> 3)) * (long)K + gch;
    const _Float16* gB = B + (n0 + (tid >> 3)) * (long)K + gch;
    const int wst = wave * 512;

#define STG_A(h, u) do {                                                          \
    gload_lds16(gA + ((h) * 128L) * K + (u) * 64,                                 \
                &sA[((u) & 1) * 16384 + (h) * 8192 + wst]);                       \
    gload_lds16(gA + ((h) * 128L + 64) * K + (u) * 64,                            \
                &sA[((u) & 1) * 16384 + (h) * 8192 + 4096 + wst]);                \
} while (0)
#define STG_B(h, u) do {                                                          \
    gload_lds16(gB + ((h) * 128L) * K + (u) * 64,                                 \
                &sB[((u) & 1) * 16384 + (h) * 8192 + wst]);                       \
    gload_lds16(gB + ((h) * 128L + 64) * K + (u) * 64,                            \
                &sB[((u) & 1) * 16384 + (h) * 8192 + 4096 + wst]);                \
} while (0)

    const int NT = K >> 6;
    // prologue: tile0 {A0,B0,B1,A1}, then tile1 {B0,B1,A0} (A1(1) comes at t=0 P1)
    STG_A(0, 0); STG_B(0, 0); STG_B(1, 0); STG_A(1, 0);
    STG_B(0, 1); STG_B(1, 1); STG_A(0, 1);
    asm volatile("s_waitcnt vmcnt(6)" ::: "memory");   // oldest 8 = tile 0
    __builtin_amdgcn_s_barrier();

    const int cs0 = (quad ^ (l16 & 7)) * 8;         // ks=0 swizzled chunk (halves)
    const int cs1 = ((4 + quad) ^ (l16 & 7)) * 8;   // ks=1

    floatx4 acc[8][4] = {};
    half8 afr[4][2], b0[2][2], b1[2][2];

    for (int t = 0; t < NT; ++t) {
        const int cur = (t & 1) * 16384;
        const _Float16* cA = &sA[cur + wm * 8192];
        const _Float16* cB = &sB[cur + hB * 8192];

        // ---------------- P1: Q(0,0) — read A(qm=0) + B(qn=0) ----------------
#pragma unroll
        for (int f = 0; f < 4; f++) {
            const _Float16* p = &cA[(f * 16 + l16) * 64];
            afr[f][0] = *(const half8*)&p[cs0];
            afr[f][1] = *(const half8*)&p[cs1];
        }
#pragma unroll
        for (int nf = 0; nf < 2; nf++) {
            const _Float16* p = &cB[((wn & 1) * 64 + nf * 16 + l16) * 64];
            b0[nf][0] = *(const half8*)&p[cs0];
            b0[nf][1] = *(const half8*)&p[cs1];
        }
        if (t + 1 < NT) STG_A(1, t + 1);           // OTHER buf: safe at P1
        __builtin_amdgcn_s_barrier();
        asm volatile("s_waitcnt lgkmcnt(0)" ::: "memory");
        __builtin_amdgcn_sched_barrier(0);
        __builtin_amdgcn_s_setprio(1);
#pragma unroll
        for (int f = 0; f < 4; f++)
#pragma unroll
            for (int nf = 0; nf < 2; nf++) {
                acc[f][nf] = mfma16(afr[f][0], b0[nf][0], acc[f][nf]);
                acc[f][nf] = mfma16(afr[f][1], b0[nf][1], acc[f][nf]);
            }
        __builtin_amdgcn_s_setprio(0);
        __builtin_amdgcn_s_barrier();

        // ---------------- P2: Q(0,1) — read B(qn=1); no stage ---------------
#pragma unroll
        for (int nf = 0; nf < 2; nf++) {
            const _Float16* p = &cB[((wn & 1) * 64 + 32 + nf * 16 + l16) * 64];
            b1[nf][0] = *(const half8*)&p[cs0];
            b1[nf][1] = *(const half8*)&p[cs1];
        }
        __builtin_amdgcn_s_barrier();
        asm volatile("s_waitcnt lgkmcnt(0)" ::: "memory");
        __builtin_amdgcn_sched_barrier(0);
        __builtin_amdgcn_s_setprio(1);
#pragma unroll
        for (int f = 0; f < 4; f++)
#pragma unroll
            for (int nf = 0; nf < 2; nf++) {
                acc[f][2 + nf] = mfma16(afr[f][0], b1[nf][0], acc[f][2 + nf]);
                acc[f][2 + nf] = mfma16(afr[f][1], b1[nf][1], acc[f][2 + nf]);
            }
        __builtin_amdgcn_s_setprio(0);
        __builtin_amdgcn_s_barrier();

        // ---------------- P3: Q(1,1) — read A(qm=1); stage B0(t+2) ----------
        // cur-buf B half0 last read at P2 (done by P2-end barrier) -> safe.
#pragma unroll
        for (int f = 0; f < 4; f++) {
            const _Float16* p = &cA[(64 + f * 16 + l16) * 64];
            afr[f][0] = *(const half8*)&p[cs0];
            afr[f][1] = *(const half8*)&p[cs1];
        }
        if (t + 2 < NT) STG_B(0, t + 2);
        __builtin_amdgcn_s_barrier();
        asm volatile("s_waitcnt lgkmcnt(0)" ::: "memory");
        __builtin_amdgcn_sched_barrier(0);
        __builtin_amdgcn_s_setprio(1);
#pragma unroll
        for (int f = 0; f < 4; f++)
#pragma unroll
            for (int nf = 0; nf < 2; nf++) {
                acc[4 + f][2 + nf] = mfma16(afr[f][0], b1[nf][0], acc[4 + f][2 + nf]);
                acc[4 + f][2 + nf] = mfma16(afr[f][1], b1[nf][1], acc[4 + f][2 + nf]);
            }
        __builtin_amdgcn_s_setprio(0);
        __builtin_amdgcn_s_barrier();

        // ---------------- P4: Q(1,0) — no reads; stage B1(t+2)+A0(t+2) ------
        // cur-buf A half0 last read at P3 (done by P3-end barrier) -> A stage
        // legal ONLY here (this was R8's race).
        if (t + 2 < NT) { STG_B(1, t + 2); STG_A(0, t + 2); }
        __builtin_amdgcn_s_barrier();
        __builtin_amdgcn_s_setprio(1);
#pragma unroll
        for (int f = 0; f < 4; f++)
#pragma unroll
            for (int nf = 0; nf < 2; nf++) {
                acc[4 + f][nf] = mfma16(afr[f][0], b0[nf][0], acc[4 + f][nf]);
                acc[4 + f][nf] = mfma16(afr[f][1], b0[nf][1], acc[4 + f][nf]);
            }
        __builtin_amdgcn_s_setprio(0);
        if (t < NT - 2)       { asm volatile("s_waitcnt vmcnt(6)" ::: "memory"); }
        else if (t == NT - 2) { asm volatile("s_waitcnt vmcnt(0)" ::: "memory"); }
        __builtin_amdgcn_s_barrier();
    }
#undef STG_A
#undef STG_B

    // epilogue: C/D layout col=lane&15, row=quad*4+reg (verified m89/m91)
#pragma unroll
    for (int mf = 0; mf < 8; mf++) {
        long row = m0 + wm * 128 + mf * 16 + quad * 4;
#pragma unroll
        for (int cn = 0; cn < 4; cn++) {
            long col = n0 + wn * 64 + cn * 16 + l16;
            if (col >= split) {
                long cv = col - split;
                long vrow = ((row >> 10) * 16 + (cv >> 6)) * 64 + (cv & 63);
                long nn = row & 1023;
                half4v pv = {(_Float16)acc[mf][cn][0], (_Float16)acc[mf][cn][1],
                             (_Float16)acc[mf][cn][2], (_Float16)acc[mf][cn][3]};
                *(half4v*)&Vt[vrow * 1024 + nn] = pv;
            } else {
#pragma unroll
                for (int r = 0; r < 4; r++)
                    Ch[(row + r) * (long)ldc + col] = (_Float16)acc[mf][cn][r];
            }
        }
    }
}

// ---------------- TN GEMM, global_load_lds pipeline (proj) ------------------
// 128x128 tile, BK=32, 256 threads, dbuf LDS — unchanged from R7.
__global__ __launch_bounds__(256, 4) void gemm_tn(
    const _Float16* __restrict__ A, const _Float16* __restrict__ B,
    _Float16* __restrict__ Ch, int ldc, _Float16* __restrict__ Vt, int split,
    float* __restrict__ Cf, const float* __restrict__ bias,
    int M, int Nn, int K)
{
    __shared__ _Float16 sA[2][128 * 32];
    __shared__ _Float16 sB[2][128 * 32];
    const int tid  = threadIdx.x;
    const int lane = tid & 63, wave = tid >> 6;
    const int quad = lane >> 4, l16 = lane & 15;
    const int wr = wave >> 1, wc = wave & 1;
    const long m0 = (long)blockIdx.x * 128, n0 = (long)blockIdx.y * 128;

    const int srow = tid >> 2;
    const int csw = ((tid & 3) ^ ((srow >> 1) & 3)) * 8;   // pre-swizzled source chunk
    const _Float16* gA0 = A + (m0 + srow) * (long)K + csw;
    const _Float16* gA1 = A + (m0 + srow + 64) * (long)K + csw;
    const _Float16* gB0 = B + (n0 + srow) * (long)K + csw;
    const _Float16* gB1 = B + (n0 + srow + 64) * (long)K + csw;
    const int wbase = wave << 4;

#define STAGE(bf, koff)                                                  \
    do {                                                                 \
        gload_lds16(gA0 + (koff), &sA[bf][wbase * 32]);                  \
        gload_lds16(gA1 + (koff), &sA[bf][(wbase + 64) * 32]);           \
        gload_lds16(gB0 + (koff), &sB[bf][wbase * 32]);                  \
        gload_lds16(gB1 + (koff), &sB[bf][(wbase + 64) * 32]);           \
    } while (0)

    const int swz = (l16 >> 1) & 3;
    const int aoff = ((quad ^ swz) * 8);

    floatx4 acc[4][4] = {};
    const int nk = K >> 5;

    STAGE(0, 0);

    for (int kk = 0; kk < nk; kk++) {
        const int cur = kk & 1;
        __syncthreads();
        if (kk + 1 < nk)
            STAGE(cur ^ 1, (long)(kk + 1) << 5);

        const _Float16* cA = &sA[cur][0];
        const _Float16* cB = &sB[cur][0];
        half8 af[4], bf[4];
#pragma unroll
        for (int t = 0; t < 4; t++)
            af[t] = *(const half8*)&cA[(wr * 64 + t * 16 + l16) * 32 + aoff];
#pragma unroll
        for (int t = 0; t < 4; t++)
            bf[t] = *(const half8*)&cB[(wc * 64 + t * 16 + l16) * 32 + aoff];
#pragma unroll
        for (int tm = 0; tm < 4; tm++)
#pragma unroll
            for (int tn = 0; tn < 4; tn++)
                acc[tm][tn] = __builtin_amdgcn_mfma_f32_16x16x32_f16(af[tm], bf[tn], acc[tm][tn], 0, 0, 0);
    }
#undef STAGE

#pragma unroll
    for (int tm = 0; tm < 4; tm++) {
        long row = m0 + wr * 64 + tm * 16 + quad * 4;
#pragma unroll
        for (int tn = 0; tn < 4; tn++) {
            long col = n0 + wc * 64 + tn * 16 + l16;
            if (Cf) {
                float bv = bias ? bias[col] : 0.f;
#pragma unroll
                for (int r = 0; r < 4; r++)
                    Cf[(row + r) * (long)Nn + col] = acc[tm][tn][r] + bv;
            } else if (col >= split) {
                long cv = col - split;
                long vrow = ((row >> 10) * 16 + (cv >> 6)) * 64 + (cv & 63);
                long nn = row & 1023;
                half4v pv = {(_Float16)acc[tm][tn][0], (_Float16)acc[tm][tn][1],
                             (_Float16)acc[tm][tn][2], (_Float16)acc[tm][tn][3]};
                *(half4v*)&Vt[vrow * 1024 + nn] = pv;
            } else {
#pragma unroll
                for (int r = 0; r < 4; r++)
                    Ch[(row + r) * (long)ldc + col] = (_Float16)acc[tm][tn][r];
            }
        }
    }
}

// ---------------- flash attention (S^T orientation) ----------------
#define CSC 0.125f
__global__ __launch_bounds__(256, 4) void flash_attn(const _Float16* __restrict__ qk,
                                                     const _Float16* __restrict__ vt,
                                                     _Float16* __restrict__ out)
{
    const int bh = blockIdx.x, b = bh >> 4, h = bh & 15;
    const int n0 = blockIdx.y * 128;
    const int tid = threadIdx.x, lane = tid & 63, wave = tid >> 6;
    const int quad = lane >> 4, l16 = lane & 15;

    __shared__ _Float16 sK[64 * 72];        // [kr][d] pad 72
    __shared__ _Float16 sVT[64 * 72];       // [d][kr] pad 72
    __shared__ _Float16 sPT[4][32 * 72];    // per-wave P^T round-trip [q][kr], reused as sOut

    half8 qf[2][2];
    const _Float16* qbase = qk + (long)(b * 1024 + n0 + wave * 32) * 2048 + h * 64;
#pragma unroll
    for (int t = 0; t < 2; t++)
#pragma unroll
        for (int s = 0; s < 2; s++)
            qf[t][s] = *(const half8*)(qbase + (long)(t * 16 + l16) * 2048 + s * 32 + quad * 8);

    const int srow = tid >> 3, scol8 = (tid & 7) * 8;
    const _Float16* kgb = qk + 1024 + h * 64 + scol8 + (long)(b * 1024 + srow) * 2048;
    const _Float16* vgb = vt + (long)(bh * 64 + srow) * 1024 + scol8;

    float m_[2] = {-1e30f, -1e30f}, l_[2] = {0.f, 0.f};
    floatx4 o[2][4] = {};

    for (int kt = 0; kt < 16; kt++) {
        const int kr0 = kt * 64;
        __syncthreads();
#pragma unroll
        for (int i = 0; i < 2; i++) {
            int r = srow + i * 32;
            *(half8*)&sK[r * 72 + scol8]  = *(const half8*)(kgb + (long)(kr0 + i * 32) * 2048);
            *(half8*)&sVT[r * 72 + scol8] = *(const half8*)(vgb + (long)(i * 32) * 1024 + kr0);
        }
        __syncthreads();

        // S^T = K Q^T: A=K (m=kr), B=Q (n=q). C-layout: kr=c*16+quad*4+r, q=t*16+l16
        floatx4 sacc[2][4] = {};
#pragma unroll
        for (int c = 0; c < 4; c++)
#pragma unroll
            for (int s = 0; s < 2; s++) {
                half8 kf = *(const half8*)&sK[(c * 16 + l16) * 72 + s * 32 + quad * 8];
                sacc[0][c] = __builtin_amdgcn_mfma_f32_16x16x32_f16(kf, qf[0][s], sacc[0][c], 0, 0, 0);
                sacc[1][c] = __builtin_amdgcn_mfma_f32_16x16x32_f16(kf, qf[1][s], sacc[1][c], 0, 0, 0);
            }

        // online softmax over kr: in-lane reduce + 2 shuffles (xor16, xor32)
#pragma unroll
        for (int t = 0; t < 2; t++) {
            float mx = -1e30f;
#pragma unroll
            for (int c = 0; c < 4; c++)
#pragma unroll
                for (int r = 0; r < 4; r++) {
                    float v = sacc[t][c][r] * CSC;
                    sacc[t][c][r] = v;
                    mx = fmaxf(mx, v);
                }
            mx = fmaxf(mx, __shfl_xor(mx, 16));
            mx = fmaxf(mx, __shfl_xor(mx, 32));
            float mn = fmaxf(m_[t], mx);
            float al = __expf(m_[t] - mn);
            m_[t] = mn;
            float rs = 0.f;
#pragma unroll
            for (int c = 0; c < 4; c++)
#pragma unroll
                for (int r = 0; r < 4; r++) {
                    float p = __expf(sacc[t][c][r] - mn);
                    sacc[t][c][r] = p;
                    rs += p;
                }
            rs += __shfl_xor(rs, 16);
            rs += __shfl_xor(rs, 32);
            l_[t] = l_[t] * al + rs;
#pragma unroll
            for (int dt = 0; dt < 4; dt++) o[t][dt] *= al;
            // pack P^T -> sPT[q][kr], one 8B half4 write per c-tile
#pragma unroll
            for (int c = 0; c < 4; c++) {
                half4v p = {(_Float16)sacc[t][c][0], (_Float16)sacc[t][c][1],
                            (_Float16)sacc[t][c][2], (_Float16)sacc[t][c][3]};
                *(half4v*)&sPT[wave][(t * 16 + l16) * 72 + c * 16 + quad * 4] = p;
            }
        }

        // PV: O^T += V^T P^T. A = V^T (m=d), B = P (n=q) from sPT.
#pragma unroll
        for (int kk = 0; kk < 2; kk++) {
            half8 pf0 = *(const half8*)&sPT[wave][(l16) * 72 + kk * 32 + quad * 8];
            half8 pf1 = *(const half8*)&sPT[wave][(16 + l16) * 72 + kk * 32 + quad * 8];
#pragma unroll
            for (int dt = 0; dt < 4; dt++) {
                half8 vf = *(const half8*)&sVT[(dt * 16 + l16) * 72 + kk * 32 + quad * 8];
                o[0][dt] = __builtin_amdgcn_mfma_f32_16x16x32_f16(vf, pf0, o[0][dt], 0, 0, 0);
                o[1][dt] = __builtin_amdgcn_mfma_f32_16x16x32_f16(vf, pf1, o[1][dt], 0, 0, 0);
            }
        }
    }

    // epilogue: normalize, per-wave LDS transpose (O^T -> O), coalesced 16B stores
#pragma unroll
    for (int t = 0; t < 2; t++) {
        float inv = 1.f / l_[t];
#pragma unroll
        for (int dt = 0; dt < 4; dt++) {
            floatx4 v = o[t][dt];
            half4v a = {(_Float16)(v[0] * inv), (_Float16)(v[1] * inv),
                        (_Float16)(v[2] * inv), (_Float16)(v[3] * inv)};
            *(half4v*)&sPT[wave][(t * 16 + l16) * 72 + dt * 16 + quad * 4] = a;
        }
    }
    __syncthreads();
#pragma unroll
    for (int i = 0; i < 4; i++) {
        int ql = i * 8 + (lane >> 3);
        int c8 = (lane & 7) * 8;
        half8 vv = *(const half8*)&sPT[wave][ql * 72 + c8];
        *(half8*)(out + (long)(b * 1024 + n0 + wave * 32 + ql) * 1024 + h * 64 + c8) = vv;
    }
}

// ---------------- launch ----------------
extern "C" void kernel_launch(void* const* d_in, const int* in_sizes, int n_in,
                              void* d_out, int out_size, void* d_ws, size_t ws_size,
                              hipStream_t stream) {
    const float* x      = (const float*)d_in[0];
    const float* w_qkv  = (const float*)d_in[1];
    const float* w_proj = (const float*)d_in[2];
    const float* b_proj = (const float*)d_in[3];

    char* ws = (char*)d_ws;
    _Float16* qkh    = (_Float16*)ws;                      // 32MB [8192][2048] (Q|K)
    _Float16* vT     = (_Float16*)(ws + 33554432);         // 16MB [128*64][1024] (V^T), by GEMM1
    _Float16* xh     = (_Float16*)(ws + 50331648);         // 16MB [8192][1024]; attnh alias
    _Float16* wqkvh  = (_Float16*)(ws + 67108864);         // 6MB [3072][1024]
    _Float16* wprojh = (_Float16*)(ws + 73400320);         // 2MB [1024][1024]
    _Float16* attnh  = xh;                                 // flash out (xh dead after GEMM1)

    cvt_all<<<12288, 256, 0, stream>>>(x, w_qkv, w_proj, xh, wqkvh, wprojh);

    // QKV GEMM (256² 8-phase): cols 0..2047 -> qkh, cols 2048..3071 -> vT transposed
    gemm256_qkv<<<dim3(32, 12), 512, 0, stream>>>(xh, wqkvh, qkh, 2048, vT, 2048, 1024);
    flash_attn<<<dim3(128, 8), 256, 0, stream>>>(qkh, vT, attnh);
    gemm_tn<<<dim3(64, 8), 256, 0, stream>>>(attnh, wprojh, nullptr, 0, nullptr, 1 << 30,
                                             (float*)d_out, b_proj, 8192, 1024, 1024);
}

// Round 4
// 236.069 us; speedup vs baseline: 1.0664x; 1.0664x over previous
//
#include <hip/hip_runtime.h>

typedef _Float16 half8 __attribute__((ext_vector_type(8)));
typedef _Float16 half4v __attribute__((ext_vector_type(4)));
typedef _Float16 half2v __attribute__((ext_vector_type(2)));
typedef float floatx4 __attribute__((ext_vector_type(4)));

#define AS3 __attribute__((address_space(3)))
#define AS1 __attribute__((address_space(1)))

// async global->LDS, 16B per lane, wave-uniform LDS base + lane*16
__device__ __forceinline__ void gload_lds16(const _Float16* g, _Float16* l) {
    __builtin_amdgcn_global_load_lds((AS1 void*)g, (AS3 void*)l, 16, 0, 0);
}

__device__ __forceinline__ floatx4 mfma16(half8 a, half8 b, floatx4 c) {
    return __builtin_amdgcn_mfma_f32_16x16x32_f16(a, b, c, 0, 0, 0);
}

// ---------------- fused f32 -> f16 convert of all three inputs ----------------
__global__ __launch_bounds__(256) void cvt_all(const float* __restrict__ x,
                                               const float* __restrict__ wq,
                                               const float* __restrict__ wp,
                                               _Float16* __restrict__ xh,
                                               _Float16* __restrict__ wqh,
                                               _Float16* __restrict__ wph) {
    long i = (long)blockIdx.x * 256 + threadIdx.x;   // float4 index
    const float4* src; half4v* dst; long off;
    if (i < 2097152)      { src = (const float4*)x;  dst = (half4v*)xh;  off = i; }
    else if (i < 2883584) { src = (const float4*)wq; dst = (half4v*)wqh; off = i - 2097152; }
    else                  { src = (const float4*)wp; dst = (half4v*)wph; off = i - 2883584; }
    float4 v = src[off];
    half4v h = {(_Float16)v.x, (_Float16)v.y, (_Float16)v.z, (_Float16)v.w};
    dst[off] = h;
}

// ---------------- 256x128 triple-buffered counted-vmcnt TN GEMM --------------
// C[M,N] = A[M,K] * B[N,K]^T.  BM=256, BN=128, BK=64, 512 threads = 4Mx2N waves
// (64x64 output per wave, acc[4][4]).  Grid = (M/256, N/128):
//   QKV  32x24 = 768 blocks = EXACTLY 3 generations @ 1 block/CU (zero tail;
//                R3's 256x256 grid 384 = 1.5 gen was the regression source)
//   proj 32x8  = 256 blocks = exactly 1 generation.
// LDS 144 KiB = 3 tile buffers x (A 32KB + B 16KB): TRIPLE buffer so tile t+2
// is staged during tile t -> the tile-boundary wait is a counted vmcnt(6)
// on loads issued ~1.5 tiles earlier (never a fresh drain; T4).
// Per K-tile: 2 phases x 16 MFMA (P1: quadrants n0/n1 reads A-frags + B01;
// P2: n2/n3 reads B23, A-frags kept live).  setprio around MFMA (T5).
// Stage stream: all 6 gload_lds of tile t+2 at t.P1.  WAR: buf (t+2)%3 was
// last ds_read during t-1 (complete before t-1's trailing barrier).  RAW:
// tile t+1's 6 loads (issued t-1.P1) retired by vmcnt(6) at t.P2-end.
// Drain: vmcnt(0) at t==NT-2 only.
// Bank swizzle (rule #21, verified 0-conflict in R1/R3): LDS chunk c of row r
// holds global chunk c^(r&7); linear gload_lds dest + pre-swizzled global
// source chunk (tid&7)^((tid>>3)&7); ds_read chunk (ks*4+quad)^(l16&7).
// Epilogue variants: Cf!=null -> f32+bias (proj); else col>=split -> Vt
// transposed (QKV V path, row>>10 = b, (col-split)>>6 = h); else Ch f16.
__global__ __launch_bounds__(512, 2) void gemm256(
    const _Float16* __restrict__ A, const _Float16* __restrict__ B,
    _Float16* __restrict__ Ch, int ldc, _Float16* __restrict__ Vt, int split,
    float* __restrict__ Cf, const float* __restrict__ bias, int Nn, int K)
{
    __shared__ _Float16 sAB[3 * 24576];   // [buf][ A:16384 | B:8192 ] halfs

    // bijective XCD swizzle (nwg % 8 == 0 for both call sites) + 8-wide
    // bx-grouping so each XCD chunk covers 8 A-panels (4MB) x all-by B
    // (<=3MB) -> both L2-resident (R3's fetch blow-up fix).
    const int nwg = gridDim.x * gridDim.y;
    int bid = blockIdx.y * gridDim.x + blockIdx.x;
    const int cpx = nwg >> 3;
    bid = (bid & 7) * cpx + (bid >> 3);
    const int gsz = gridDim.y << 3;
    const int bxg = bid / gsz;
    const int rem = bid - bxg * gsz;
    const int by = rem >> 3;
    const int bx = (bxg << 3) + (rem & 7);

    const int tid = threadIdx.x;
    const int lane = tid & 63, wave = tid >> 6;
    const int quad = lane >> 4, l16 = lane & 15;
    const int wm = wave >> 1, wn = wave & 1;      // 4M x 2N wave grid
    const long m0 = (long)bx * 256, n0 = (long)by * 128;

    // pre-swizzled global source chunk (see header comment)
    const int gch = ((tid & 7) ^ ((tid >> 3) & 7)) * 8;
    const _Float16* gA = A + (m0 + (tid >> 3)) * (long)K + gch;
    const _Float16* gB = B + (n0 + (tid >> 3)) * (long)K + gch;
    const int wst = wave * 512;   // halfs: wave's linear 1KB slice of a slab

    // 6 loads per tile: A slabs 0..3 (64 rows each), B slabs 0..1
#define STAGE(sb, u) do {                                                     \
    const long ko = (long)(u) * 64;                                           \
    _Float16* d = &sAB[(sb) * 24576];                                         \
    gload_lds16(gA + ko,                 d + wst);                            \
    gload_lds16(gA +  64 * (long)K + ko, d + 4096  + wst);                    \
    gload_lds16(gA + 128 * (long)K + ko, d + 8192  + wst);                    \
    gload_lds16(gA + 192 * (long)K + ko, d + 12288 + wst);                    \
    gload_lds16(gB + ko,                 d + 16384 + wst);                    \
    gload_lds16(gB +  64 * (long)K + ko, d + 20480 + wst);                    \
} while (0)

    const int NT = K >> 6;
    STAGE(0, 0); STAGE(1, 1);
    asm volatile("s_waitcnt vmcnt(6)" ::: "memory");   // tile 0 resident
    __builtin_amdgcn_s_barrier();

    const int cs0 = (quad ^ (l16 & 7)) * 8;         // ks=0 swizzled chunk
    const int cs1 = ((4 + quad) ^ (l16 & 7)) * 8;   // ks=1

    floatx4 acc[4][4] = {};
    half8 afr[4][2], bf0[2][2], bf1[2][2];

    int cb = 0, sb = 2;   // cur buf = t%3, stage buf = (t+2)%3
    for (int t = 0; t < NT; ++t) {
        const _Float16* cA = &sAB[cb * 24576 + wm * 4096];
        const _Float16* cB = &sAB[cb * 24576 + 16384 + wn * 4096];

        // ---- P1: cols 0..31 — read A-frags (8) + B01 (4); stage tile t+2 ----
#pragma unroll
        for (int f = 0; f < 4; f++) {
            const _Float16* p = &cA[(f * 16 + l16) * 64];
            afr[f][0] = *(const half8*)&p[cs0];
            afr[f][1] = *(const half8*)&p[cs1];
        }
#pragma unroll
        for (int nf = 0; nf < 2; nf++) {
            const _Float16* p = &cB[(nf * 16 + l16) * 64];
            bf0[nf][0] = *(const half8*)&p[cs0];
            bf0[nf][1] = *(const half8*)&p[cs1];
        }
        if (t + 2 < NT) STAGE(sb, t + 2);
        __builtin_amdgcn_s_barrier();
        asm volatile("s_waitcnt lgkmcnt(0)" ::: "memory");
        __builtin_amdgcn_sched_barrier(0);
        __builtin_amdgcn_s_setprio(1);
#pragma unroll
        for (int f = 0; f < 4; f++)
#pragma unroll
            for (int nf = 0; nf < 2; nf++) {
                acc[f][nf] = mfma16(afr[f][0], bf0[nf][0], acc[f][nf]);
                acc[f][nf] = mfma16(afr[f][1], bf0[nf][1], acc[f][nf]);
            }
        __builtin_amdgcn_s_setprio(0);
        __builtin_amdgcn_s_barrier();

        // ---- P2: cols 32..63 — read B23 (4); A-frags still live -------------
#pragma unroll
        for (int nf = 0; nf < 2; nf++) {
            const _Float16* p = &cB[((2 + nf) * 16 + l16) * 64];
            bf1[nf][0] = *(const half8*)&p[cs0];
            bf1[nf][1] = *(const half8*)&p[cs1];
        }
        __builtin_amdgcn_s_barrier();
        asm volatile("s_waitcnt lgkmcnt(0)" ::: "memory");
        __builtin_amdgcn_sched_barrier(0);
        __builtin_amdgcn_s_setprio(1);
#pragma unroll
        for (int f = 0; f < 4; f++)
#pragma unroll
            for (int nf = 0; nf < 2; nf++) {
                acc[f][2 + nf] = mfma16(afr[f][0], bf1[nf][0], acc[f][2 + nf]);
                acc[f][2 + nf] = mfma16(afr[f][1], bf1[nf][1], acc[f][2 + nf]);
            }
        __builtin_amdgcn_s_setprio(0);
        if (t + 2 < NT)       { asm volatile("s_waitcnt vmcnt(6)" ::: "memory"); }
        else if (t == NT - 2) { asm volatile("s_waitcnt vmcnt(0)" ::: "memory"); }
        __builtin_amdgcn_s_barrier();
        cb = (cb + 1 == 3) ? 0 : cb + 1;
        sb = (sb + 1 == 3) ? 0 : sb + 1;
    }
#undef STAGE

    // epilogue: C/D layout col=lane&15, row=quad*4+reg (verified m89/m91)
#pragma unroll
    for (int f = 0; f < 4; f++) {
        long row = m0 + wm * 64 + f * 16 + quad * 4;
#pragma unroll
        for (int cn = 0; cn < 4; cn++) {
            long col = n0 + wn * 64 + cn * 16 + l16;
            if (Cf) {
                float bv = bias ? bias[col] : 0.f;
#pragma unroll
                for (int r = 0; r < 4; r++)
                    Cf[(row + r) * (long)Nn + col] = acc[f][cn][r] + bv;
            } else if (col >= split) {
                // transposed V write: Vt[(b*16+h)*64+d][n], n = 4 consecutive rows
                long cv = col - split;
                long vrow = ((row >> 10) * 16 + (cv >> 6)) * 64 + (cv & 63);
                long nn = row & 1023;
                half4v pv = {(_Float16)acc[f][cn][0], (_Float16)acc[f][cn][1],
                             (_Float16)acc[f][cn][2], (_Float16)acc[f][cn][3]};
                *(half4v*)&Vt[vrow * 1024 + nn] = pv;
            } else {
#pragma unroll
                for (int r = 0; r < 4; r++)
                    Ch[(row + r) * (long)ldc + col] = (_Float16)acc[f][cn][r];
            }
        }
    }
}

// ---------------- flash attention (S^T orientation) ----------------
#define CSC 0.125f
__global__ __launch_bounds__(256, 4) void flash_attn(const _Float16* __restrict__ qk,
                                                     const _Float16* __restrict__ vt,
                                                     _Float16* __restrict__ out)
{
    const int bh = blockIdx.x, b = bh >> 4, h = bh & 15;
    const int n0 = blockIdx.y * 128;
    const int tid = threadIdx.x, lane = tid & 63, wave = tid >> 6;
    const int quad = lane >> 4, l16 = lane & 15;

    __shared__ _Float16 sK[64 * 72];        // [kr][d] pad 72
    __shared__ _Float16 sVT[64 * 72];       // [d][kr] pad 72
    __shared__ _Float16 sPT[4][32 * 72];    // per-wave P^T round-trip [q][kr], reused as sOut

    half8 qf[2][2];
    const _Float16* qbase = qk + (long)(b * 1024 + n0 + wave * 32) * 2048 + h * 64;
#pragma unroll
    for (int t = 0; t < 2; t++)
#pragma unroll
        for (int s = 0; s < 2; s++)
            qf[t][s] = *(const half8*)(qbase + (long)(t * 16 + l16) * 2048 + s * 32 + quad * 8);

    const int srow = tid >> 3, scol8 = (tid & 7) * 8;
    const _Float16* kgb = qk + 1024 + h * 64 + scol8 + (long)(b * 1024 + srow) * 2048;
    const _Float16* vgb = vt + (long)(bh * 64 + srow) * 1024 + scol8;

    float m_[2] = {-1e30f, -1e30f}, l_[2] = {0.f, 0.f};
    floatx4 o[2][4] = {};

    for (int kt = 0; kt < 16; kt++) {
        const int kr0 = kt * 64;
        __syncthreads();
#pragma unroll
        for (int i = 0; i < 2; i++) {
            int r = srow + i * 32;
            *(half8*)&sK[r * 72 + scol8]  = *(const half8*)(kgb + (long)(kr0 + i * 32) * 2048);
            *(half8*)&sVT[r * 72 + scol8] = *(const half8*)(vgb + (long)(i * 32) * 1024 + kr0);
        }
        __syncthreads();

        // S^T = K Q^T: A=K (m=kr), B=Q (n=q). C-layout: kr=c*16+quad*4+r, q=t*16+l16
        floatx4 sacc[2][4] = {};
#pragma unroll
        for (int c = 0; c < 4; c++)
#pragma unroll
            for (int s = 0; s < 2; s++) {
                half8 kf = *(const half8*)&sK[(c * 16 + l16) * 72 + s * 32 + quad * 8];
                sacc[0][c] = __builtin_amdgcn_mfma_f32_16x16x32_f16(kf, qf[0][s], sacc[0][c], 0, 0, 0);
                sacc[1][c] = __builtin_amdgcn_mfma_f32_16x16x32_f16(kf, qf[1][s], sacc[1][c], 0, 0, 0);
            }

        // online softmax over kr: in-lane reduce + 2 shuffles (xor16, xor32)
#pragma unroll
        for (int t = 0; t < 2; t++) {
            float mx = -1e30f;
#pragma unroll
            for (int c = 0; c < 4; c++)
#pragma unroll
                for (int r = 0; r < 4; r++) {
                    float v = sacc[t][c][r] * CSC;
                    sacc[t][c][r] = v;
                    mx = fmaxf(mx, v);
                }
            mx = fmaxf(mx, __shfl_xor(mx, 16));
            mx = fmaxf(mx, __shfl_xor(mx, 32));
            float mn = fmaxf(m_[t], mx);
            float al = __expf(m_[t] - mn);
            m_[t] = mn;
            float rs = 0.f;
#pragma unroll
            for (int c = 0; c < 4; c++)
#pragma unroll
                for (int r = 0; r < 4; r++) {
                    float p = __expf(sacc[t][c][r] - mn);
                    sacc[t][c][r] = p;
                    rs += p;
                }
            rs += __shfl_xor(rs, 16);
            rs += __shfl_xor(rs, 32);
            l_[t] = l_[t] * al + rs;
#pragma unroll
            for (int dt = 0; dt < 4; dt++) o[t][dt] *= al;
            // pack P^T -> sPT[q][kr], one 8B half4 write per c-tile
#pragma unroll
            for (int c = 0; c < 4; c++) {
                half4v p = {(_Float16)sacc[t][c][0], (_Float16)sacc[t][c][1],
                            (_Float16)sacc[t][c][2], (_Float16)sacc[t][c][3]};
                *(half4v*)&sPT[wave][(t * 16 + l16) * 72 + c * 16 + quad * 4] = p;
            }
        }

        // PV: O^T += V^T P^T. A = V^T (m=d), B = P (n=q) from sPT.
#pragma unroll
        for (int kk = 0; kk < 2; kk++) {
            half8 pf0 = *(const half8*)&sPT[wave][(l16) * 72 + kk * 32 + quad * 8];
            half8 pf1 = *(const half8*)&sPT[wave][(16 + l16) * 72 + kk * 32 + quad * 8];
#pragma unroll
            for (int dt = 0; dt < 4; dt++) {
                half8 vf = *(const half8*)&sVT[(dt * 16 + l16) * 72 + kk * 32 + quad * 8];
                o[0][dt] = __builtin_amdgcn_mfma_f32_16x16x32_f16(vf, pf0, o[0][dt], 0, 0, 0);
                o[1][dt] = __builtin_amdgcn_mfma_f32_16x16x32_f16(vf, pf1, o[1][dt], 0, 0, 0);
            }
        }
    }

    // epilogue: normalize, per-wave LDS transpose (O^T -> O), coalesced 16B stores
#pragma unroll
    for (int t = 0; t < 2; t++) {
        float inv = 1.f / l_[t];
#pragma unroll
        for (int dt = 0; dt < 4; dt++) {
            floatx4 v = o[t][dt];
            half4v a = {(_Float16)(v[0] * inv), (_Float16)(v[1] * inv),
                        (_Float16)(v[2] * inv), (_Float16)(v[3] * inv)};
            *(half4v*)&sPT[wave][(t * 16 + l16) * 72 + dt * 16 + quad * 4] = a;
        }
    }
    __syncthreads();
#pragma unroll
    for (int i = 0; i < 4; i++) {
        int ql = i * 8 + (lane >> 3);
        int c8 = (lane & 7) * 8;
        half8 vv = *(const half8*)&sPT[wave][ql * 72 + c8];
        *(half8*)(out + (long)(b * 1024 + n0 + wave * 32 + ql) * 1024 + h * 64 + c8) = vv;
    }
}

// ---------------- launch ----------------
extern "C" void kernel_launch(void* const* d_in, const int* in_sizes, int n_in,
                              void* d_out, int out_size, void* d_ws, size_t ws_size,
                              hipStream_t stream) {
    const float* x      = (const float*)d_in[0];
    const float* w_qkv  = (const float*)d_in[1];
    const float* w_proj = (const float*)d_in[2];
    const float* b_proj = (const float*)d_in[3];

    char* ws = (char*)d_ws;
    _Float16* qkh    = (_Float16*)ws;                      // 32MB [8192][2048] (Q|K)
    _Float16* vT     = (_Float16*)(ws + 33554432);         // 16MB [128*64][1024] (V^T), by GEMM1
    _Float16* xh     = (_Float16*)(ws + 50331648);         // 16MB [8192][1024]; attnh alias
    _Float16* wqkvh  = (_Float16*)(ws + 67108864);         // 6MB [3072][1024]
    _Float16* wprojh = (_Float16*)(ws + 73400320);         // 2MB [1024][1024]
    _Float16* attnh  = xh;                                 // flash out (xh dead after GEMM1)

    cvt_all<<<12288, 256, 0, stream>>>(x, w_qkv, w_proj, xh, wqkvh, wprojh);

    // QKV GEMM: cols 0..2047 -> qkh row-major, cols 2048..3071 -> vT transposed
    gemm256<<<dim3(32, 24), 512, 0, stream>>>(xh, wqkvh, qkh, 2048, vT, 2048,
                                              nullptr, nullptr, 3072, 1024);
    flash_attn<<<dim3(128, 8), 256, 0, stream>>>(qkh, vT, attnh);
    // proj GEMM: f32 + bias epilogue
    gemm256<<<dim3(32, 8), 512, 0, stream>>>(attnh, wprojh, nullptr, 0, nullptr, 1 << 30,
                                             (float*)d_out, b_proj, 1024, 1024);
}